// Round 1
// baseline (2346.691 us; speedup 1.0000x reference)
//
#include <hip/hip_runtime.h>

#define FEAT 28   // features per table row
#define LVL  16   // levels

// One thread per (point, level). blockIdx.y = level -> level-major dispatch
// order so each hashed level's 58.7MB table stays resident in the 256MB L3
// while that level's gathers are in flight.
__global__ __launch_bounds__(256) void hashgrid_kernel(
    const float* __restrict__ inputs,     // (N,3) f32
    const float* __restrict__ memory,     // (total, 28) f32
    const int*   __restrict__ offsets,    // (17) i32
    const int*   __restrict__ res_list,   // (16,3) i32
    const float* __restrict__ side_list,  // (16) f32
    float*       __restrict__ out,        // (N,16,28) f32
    int N)
{
    const int l = blockIdx.y;
    const int n = blockIdx.x * blockDim.x + threadIdx.x;
    if (n >= N) return;

    // Level metadata: uniform across the block -> scalar loads.
    const int   base = offsets[l];
    const unsigned size = (unsigned)(offsets[l + 1] - base);
    const int r0 = res_list[l * 3 + 0];
    const int r1 = res_list[l * 3 + 1];
    const int r2 = res_list[l * 3 + 2];
    const float side = side_list[l];

    // BOUNDS[:,0] from the reference (not passed as an input).
    const float bmin0 = -3.0f, bmin1 = -4.0f, bmin2 = -2.0f;

    const float x = inputs[n * 3 + 0];
    const float y = inputs[n * 3 + 1];
    const float z = inputs[n * 3 + 2];

    // IEEE division to match the numpy reference exactly (floor() cell choice
    // must not flip vs reference).
    const float p0 = (x - bmin0) / side;
    const float p1 = (y - bmin1) / side;
    const float p2 = (z - bmin2) / side;
    const float g0 = floorf(p0), g1 = floorf(p1), g2 = floorf(p2);
    const float f0 = p0 - g0, f1 = p1 - g1, f2 = p2 - g2;
    const int i0 = (int)g0, i1 = (int)g1, i2 = (int)g2;

    // use_direct = prod(res as f32) <= size  (reference semantics)
    const bool direct = (((float)r0 * (float)r1) * (float)r2) <= (float)size;

    const unsigned ur0   = (unsigned)r0;
    const unsigned ur0r1 = (unsigned)(r0 * r1);

    float4 acc[7];
#pragma unroll
    for (int j = 0; j < 7; ++j) acc[j] = make_float4(0.f, 0.f, 0.f, 0.f);

#pragma unroll
    for (int c = 0; c < 8; ++c) {
        const int d0 = (c >> 0) & 1, d1 = (c >> 1) & 1, d2 = (c >> 2) & 1;
        const int c0 = min(max(i0 + d0, 0), r0 - 1);
        const int c1 = min(max(i1 + d1, 0), r1 - 1);
        const int c2 = min(max(i2 + d2, 0), r2 - 1);
        const unsigned u0 = (unsigned)c0, u1 = (unsigned)c1, u2 = (unsigned)c2;

        const unsigned didx = u0 + u1 * ur0 + u2 * ur0r1;
        const unsigned hidx =
            (u0 * 1u ^ u1 * 2654435761u ^ u2 * 805459861u) % size;
        const int idx = (int)(direct ? didx : hidx) + base;

        // weight: ((wx*wy)*wz), same order as reference prod over last axis
        float w = (d0 ? f0 : 1.0f - f0) * (d1 ? f1 : 1.0f - f1);
        w *= (d2 ? f2 : 1.0f - f2);

        // 112B row = 7 x float4; idx*112 is 16B aligned.
        const float4* row =
            (const float4*)(memory + (size_t)idx * (size_t)FEAT);
#pragma unroll
        for (int j = 0; j < 7; ++j) {
            const float4 v = row[j];
            acc[j].x += w * v.x;
            acc[j].y += w * v.y;
            acc[j].z += w * v.z;
            acc[j].w += w * v.w;
        }
    }

    float4* op = (float4*)(out + ((size_t)n * LVL + l) * (size_t)FEAT);
#pragma unroll
    for (int j = 0; j < 7; ++j) op[j] = acc[j];
}

extern "C" void kernel_launch(void* const* d_in, const int* in_sizes, int n_in,
                              void* d_out, int out_size, void* d_ws, size_t ws_size,
                              hipStream_t stream) {
    const float* inputs    = (const float*)d_in[0];
    const float* memory    = (const float*)d_in[1];
    const int*   offsets   = (const int*)d_in[2];
    const int*   res_list  = (const int*)d_in[3];
    const float* side_list = (const float*)d_in[4];
    float* out = (float*)d_out;

    const int N = in_sizes[0] / 3;           // (N,3) points
    const int L = in_sizes[4];               // 16 levels

    dim3 block(256);
    dim3 grid((N + 255) / 256, L);           // x fastest -> level-major order
    hipLaunchKernelGGL(hashgrid_kernel, grid, block, 0, stream,
                       inputs, memory, offsets, res_list, side_list, out, N);
}

// Round 3
// 744.902 us; speedup vs baseline: 3.1503x; 3.1503x over previous
//
#include <hip/hip_runtime.h>

#define FEAT 28   // features per table row
#define LVL  16   // levels
#define PTS_PER_BLOCK 64
#define THREADS (PTS_PER_BLOCK * 7)   // 448 = 7 waves

typedef float f32x4 __attribute__((ext_vector_type(4)));

// One thread per (point, level, float4-slice). blockIdx.y = level ->
// level-major dispatch so each hashed level's 58.7MB table stays L3-resident.
// 8 independent 16B gathers per thread (one per corner) for deep MLP.
__global__ __launch_bounds__(THREADS) void hashgrid_kernel(
    const float* __restrict__ inputs,     // (N,3) f32
    const float* __restrict__ memory,     // (total, 28) f32
    const int*   __restrict__ offsets,    // (17) i32
    const int*   __restrict__ res_list,   // (16,3) i32
    const float* __restrict__ side_list,  // (16) f32
    float*       __restrict__ out,        // (N,16,28) f32
    int N)
{
    const int l   = blockIdx.y;
    const int tid = threadIdx.x;
    const int pl  = tid / 7;              // local point 0..63
    const int j   = tid - pl * 7;         // float4 slice 0..6
    const int n   = blockIdx.x * PTS_PER_BLOCK + pl;
    if (n >= N) return;

    // Level metadata: uniform across block -> scalar loads.
    const int      base = offsets[l];
    const unsigned size = (unsigned)(offsets[l + 1] - base);
    const int r0 = res_list[l * 3 + 0];
    const int r1 = res_list[l * 3 + 1];
    const int r2 = res_list[l * 3 + 2];
    const float side = side_list[l];

    // BOUNDS[:,0] from the reference.
    const float bmin0 = -3.0f, bmin1 = -4.0f, bmin2 = -2.0f;

    const float x = inputs[n * 3 + 0];
    const float y = inputs[n * 3 + 1];
    const float z = inputs[n * 3 + 2];

    // IEEE division: must match numpy's floor-cell choice bit-for-bit.
    const float p0 = (x - bmin0) / side;
    const float p1 = (y - bmin1) / side;
    const float p2 = (z - bmin2) / side;
    const float g0 = floorf(p0), g1 = floorf(p1), g2 = floorf(p2);
    const float f0 = p0 - g0, f1 = p1 - g1, f2 = p2 - g2;
    const int i0 = (int)g0, i1 = (int)g1, i2 = (int)g2;

    const bool direct = (((float)r0 * (float)r1) * (float)r2) <= (float)size;
    const unsigned ur0   = (unsigned)r0;
    const unsigned ur0r1 = (unsigned)(r0 * r1);

    // Precompute all 8 corner indices + weights (uniform across the 7 lanes
    // of a point; VALU is nearly idle so redundancy is free).
    int      idx8[8];
    float    w8[8];
#pragma unroll
    for (int c = 0; c < 8; ++c) {
        const int d0 = (c >> 0) & 1, d1 = (c >> 1) & 1, d2 = (c >> 2) & 1;
        const int c0 = min(max(i0 + d0, 0), r0 - 1);
        const int c1 = min(max(i1 + d1, 0), r1 - 1);
        const int c2 = min(max(i2 + d2, 0), r2 - 1);
        const unsigned u0 = (unsigned)c0, u1 = (unsigned)c1, u2 = (unsigned)c2;
        const unsigned didx = u0 + u1 * ur0 + u2 * ur0r1;
        const unsigned hidx =
            (u0 * 1u ^ u1 * 2654435761u ^ u2 * 805459861u) % size;
        idx8[c] = (int)(direct ? didx : hidx) + base;
        float w = (d0 ? f0 : 1.0f - f0) * (d1 ? f1 : 1.0f - f1);
        w *= (d2 ? f2 : 1.0f - f2);
        w8[c] = w;
    }

    // Issue all 8 independent 16B gathers, then accumulate in reference
    // order (c = 0..7).
    f32x4 v[8];
#pragma unroll
    for (int c = 0; c < 8; ++c) {
        const f32x4* row =
            (const f32x4*)(memory + (size_t)idx8[c] * (size_t)FEAT);
        v[c] = row[j];
    }

    f32x4 acc = (f32x4)(0.0f);
#pragma unroll
    for (int c = 0; c < 8; ++c) {
        acc += w8[c] * v[c];
    }

    f32x4* op = (f32x4*)(out + ((size_t)n * LVL + l) * (size_t)FEAT) + j;
    __builtin_nontemporal_store(acc, op);
}

extern "C" void kernel_launch(void* const* d_in, const int* in_sizes, int n_in,
                              void* d_out, int out_size, void* d_ws, size_t ws_size,
                              hipStream_t stream) {
    const float* inputs    = (const float*)d_in[0];
    const float* memory    = (const float*)d_in[1];
    const int*   offsets   = (const int*)d_in[2];
    const int*   res_list  = (const int*)d_in[3];
    const float* side_list = (const float*)d_in[4];
    float* out = (float*)d_out;

    const int N = in_sizes[0] / 3;           // (N,3) points
    const int L = in_sizes[4];               // 16 levels

    dim3 block(THREADS);
    dim3 grid((N + PTS_PER_BLOCK - 1) / PTS_PER_BLOCK, L);
    hipLaunchKernelGGL(hashgrid_kernel, grid, block, 0, stream,
                       inputs, memory, offsets, res_list, side_list, out, N);
}